// Round 2
// baseline (42224.985 us; speedup 1.0000x reference)
//
#include <hip/hip_runtime.h>
#include <stdint.h>

#define N_NODES 4096
#define BATCH   512
#define STEPS   120
#define LEAK    0.01f
#define MAX_EDGES 131072   // edge buffer capacity (nnz <= 131072 by construction)

// d_ws layout:
//   [0,16)    : int counter[0]=nnz (atomic), counter[1]=nPairs (uint4 pairs)
//   [256, ..) : edge records uint2 { (tgt<<16)|src , f32 bits of val }

__global__ void init_counter(int* __restrict__ counter) {
    if (threadIdx.x < 4) counter[threadIdx.x] = 0;
}

__global__ void extract_edges(const float* __restrict__ W,
                              uint2* __restrict__ edges,
                              int* __restrict__ counter, int cap) {
    int idx = (int)(blockIdx.x * 256 + threadIdx.x);   // covers 4096*4096
    float w = W[idx];
    if (w != 0.0f) {
        unsigned t = (unsigned)(idx >> 12);
        unsigned s = (unsigned)(idx & (N_NODES - 1));
        int p = atomicAdd(counter, 1);
        if (p < cap)
            edges[p] = make_uint2((t << 16) | s, __float_as_uint(w));
    }
}

__global__ void pad_edges(uint2* __restrict__ edges,
                          int* __restrict__ counter, int cap) {
    int nnz = counter[0];
    if (nnz > cap) nnz = cap;
    int padded = (nnz + 1023) & ~1023;                 // multiple of 1024 edges
    if (padded > cap) padded = cap & ~1023;
    for (int i = nnz + (int)threadIdx.x; i < padded; i += (int)blockDim.x)
        edges[i] = make_uint2(0u, 0u);                 // val=0 -> harmless
    if (threadIdx.x == 0) counter[1] = padded >> 1;    // number of uint4 pairs
}

__device__ __forceinline__ float mml_f(float x) {
    float y = (x < 0.0f) ? (LEAK * x) : x;
    if (x > 0.5f) y = 1.0f - 0.25f / x;                // x>0.5 => max(x,0.5)=x
    return y;
}

// One block owns 2 batch columns; full 120-step recurrence lives in LDS.
__global__ void __launch_bounds__(512, 1)
iterate_kernel(const float* __restrict__ X_full,       // (512, 4096) row-major
               const float* __restrict__ bias,         // (4096)
               const uint2* __restrict__ edges,
               const int* __restrict__ counter,
               float* __restrict__ out) {              // (512, 4096) row-major
    __shared__ float2 sX[N_NODES];                     // 32 KB: X_cur, 2 cols interleaved
    __shared__ float  sAcc[N_NODES * 2];               // 32 KB: accumulator

    const int tid  = (int)threadIdx.x;                 // 0..511
    const int colb = (int)blockIdx.x * 2;
    const int nPairs = counter[1];                     // uniform, multiple of 512
    const uint4* ep = (const uint4*)edges;             // 2 edges per uint4

    const int tt = tid & 255;
    const int c  = tid >> 8;
    const float* xrow = X_full + (size_t)(colb + c) * N_NODES;

    // register-cache X_bias for my 16 slots; init accumulator with it
    float xb[16];
    #pragma unroll
    for (int j = 0; j < 16; ++j) {
        int t = tt + 256 * j;
        xb[j] = xrow[t] + bias[t];
        sAcc[t * 2 + c] = xb[j];
    }
    __syncthreads();

    for (int step = 0; step < STEPS; ++step) {
        if (step > 0) {
            // edge-parallel accumulate: acc[tgt] += val * X[src]  (both cols)
            for (int i = tid; i < nPairs; i += 512) {
                uint4 p = ep[i];
                unsigned ts0 = p.x; float v0 = __uint_as_float(p.y);
                unsigned ts1 = p.z; float v1 = __uint_as_float(p.w);
                float2 x0 = sX[ts0 & 0xffffu];
                float2 x1 = sX[ts1 & 0xffffu];
                unsigned t0 = ts0 >> 16, t1 = ts1 >> 16;
                atomicAdd(&sAcc[t0 * 2 + 0], v0 * x0.x);
                atomicAdd(&sAcc[t0 * 2 + 1], v0 * x0.y);
                atomicAdd(&sAcc[t1 * 2 + 0], v1 * x1.x);
                atomicAdd(&sAcc[t1 * 2 + 1], v1 * x1.y);
            }
            __syncthreads();
        }
        // activation + reset accumulator to X_bias
        float* sXf = (float*)sX;
        #pragma unroll
        for (int j = 0; j < 16; ++j) {
            int idx = (tt + 256 * j) * 2 + c;
            float x = sAcc[idx];
            sXf[idx] = mml_f(x);
            sAcc[idx] = xb[j];
        }
        __syncthreads();
    }

    // out[b][t] = X_ss[t][b]  (row b contiguous -> coalesced in t)
    const float* sXf = (const float*)sX;
    float* orow = out + (size_t)(colb + c) * N_NODES;
    #pragma unroll
    for (int j = 0; j < 16; ++j) {
        int t = tt + 256 * j;
        orow[t] = sXf[t * 2 + c];
    }
}

extern "C" void kernel_launch(void* const* d_in, const int* in_sizes, int n_in,
                              void* d_out, int out_size, void* d_ws, size_t ws_size,
                              hipStream_t stream) {
    // Identify inputs by element count (robust to ordering).
    const float* X_full = nullptr;
    const float* W      = nullptr;
    const float* bias   = nullptr;
    for (int i = 0; i < n_in; ++i) {
        if      (in_sizes[i] == N_NODES * N_NODES) W      = (const float*)d_in[i];
        else if (in_sizes[i] == BATCH * N_NODES)   X_full = (const float*)d_in[i];
        else if (in_sizes[i] == N_NODES)           bias   = (const float*)d_in[i];
    }

    int*   counter = (int*)d_ws;
    uint2* edges   = (uint2*)((char*)d_ws + 256);

    // Edge capacity bounded by actual workspace size (no OOB writes ever).
    int cap = 0;
    if (ws_size > 256) {
        size_t c = (ws_size - 256) / sizeof(uint2);
        cap = (c > MAX_EDGES) ? MAX_EDGES : (int)c;
    }

    init_counter<<<1, 64, 0, stream>>>(counter);
    extract_edges<<<(N_NODES * N_NODES) / 256, 256, 0, stream>>>(W, edges, counter, cap);
    pad_edges<<<1, 1024, 0, stream>>>(edges, counter, cap);
    iterate_kernel<<<BATCH / 2, 512, 0, stream>>>(X_full, bias, edges, counter,
                                                  (float*)d_out);
}

// Round 3
// 15110.814 us; speedup vs baseline: 2.7944x; 2.7944x over previous
//
#include <hip/hip_runtime.h>
#include <stdint.h>

#define N_NODES 4096
#define BATCH   512
#define STEPS   120
#define LEAK    0.01f
#define NMASK   (N_NODES - 1)

// d_ws layout:
//   deg    : int[4096]    @ 0
//   cursor : int[4096]    @ 16384
//   rowptr : int[4097]    @ 32768
//   E      : u32[131072]  @ 49408   (packed: weight f32 with low 12 mantissa
//                                    bits replaced by src index, RN-rounded)

__global__ void zero_meta(int* __restrict__ p) {
    int i = (int)(blockIdx.x * 256 + threadIdx.x);   // zero deg+cursor (8192)
    if (i < 2 * N_NODES) p[i] = 0;
}

__global__ void count_deg(const float* __restrict__ W, int* __restrict__ deg) {
    int idx = (int)(blockIdx.x * 256 + threadIdx.x); // 4096*4096 elements
    float w = W[idx];
    if (w != 0.0f) atomicAdd(&deg[idx >> 12], 1);
}

__global__ void scan_rowptr(const int* __restrict__ deg, int* __restrict__ rowptr) {
    __shared__ int part[1024];
    int tid = (int)threadIdx.x;
    int base = tid * 4;
    int d0 = deg[base], d1 = deg[base + 1], d2 = deg[base + 2], d3 = deg[base + 3];
    int s = d0 + d1 + d2 + d3;
    part[tid] = s;
    __syncthreads();
    for (int off = 1; off < 1024; off <<= 1) {
        int v = (tid >= off) ? part[tid - off] : 0;
        __syncthreads();
        part[tid] += v;
        __syncthreads();
    }
    int excl = part[tid] - s;
    rowptr[base]     = excl;
    rowptr[base + 1] = excl + d0;
    rowptr[base + 2] = excl + d0 + d1;
    rowptr[base + 3] = excl + d0 + d1 + d2;
    if (tid == 1023) rowptr[N_NODES] = part[1023];
}

__global__ void scatter_edges(const float* __restrict__ W,
                              const int* __restrict__ rowptr,
                              int* __restrict__ cursor,
                              unsigned* __restrict__ E) {
    int idx = (int)(blockIdx.x * 256 + threadIdx.x);
    float w = W[idx];
    if (w != 0.0f) {
        int t = idx >> 12;
        unsigned s = (unsigned)(idx & NMASK);
        int pos = rowptr[t] + atomicAdd(&cursor[t], 1);
        unsigned wb = (__float_as_uint(w) + 0x800u) & 0xFFFFF000u; // RN to 12-bit trunc
        E[pos] = wb | s;
    }
}

__device__ __forceinline__ float mml_f(float x) {
    float y = (x < 0.0f) ? (LEAK * x) : x;
    if (x > 0.5f) y = 1.0f - 0.25f / x;              // x>0.5 => max(x,0.5)=x
    return y;
}
__device__ __forceinline__ float2 mml2(float2 v) {
    return make_float2(mml_f(v.x), mml_f(v.y));
}

// One block = 2 batch columns; thread owns 4 target rows; double-buffered X in
// LDS; zero atomics; one barrier per step.
__global__ void __launch_bounds__(1024, 1)
iterate_kernel(const float* __restrict__ X_full,     // (512, 4096) row-major
               const float* __restrict__ bias,       // (4096)
               const unsigned* __restrict__ E,
               const int* __restrict__ rowptr,
               float* __restrict__ out) {            // (512, 4096) row-major
    __shared__ float2 bufA[N_NODES];                 // 32 KB
    __shared__ float2 bufB[N_NODES];                 // 32 KB

    const int tid  = (int)threadIdx.x;               // 0..1023
    const int colb = (int)blockIdx.x * 2;
    const int r0   = tid * 4;

    float4 xa = ((const float4*)(X_full + (size_t)colb * N_NODES))[tid];
    float4 xc = ((const float4*)(X_full + (size_t)(colb + 1) * N_NODES))[tid];
    float4 bb = ((const float4*)bias)[tid];
    float2 xb0 = make_float2(xa.x + bb.x, xc.x + bb.x);
    float2 xb1 = make_float2(xa.y + bb.y, xc.y + bb.y);
    float2 xb2 = make_float2(xa.z + bb.z, xc.z + bb.z);
    float2 xb3 = make_float2(xa.w + bb.w, xc.w + bb.w);

    int rp0 = rowptr[r0],     rp1 = rowptr[r0 + 1], rp2 = rowptr[r0 + 2];
    int rp3 = rowptr[r0 + 3], rp4 = rowptr[r0 + 4];

    // X1 = mml(xb)
    bufA[r0]     = mml2(xb0);
    bufA[r0 + 1] = mml2(xb1);
    bufA[r0 + 2] = mml2(xb2);
    bufA[r0 + 3] = mml2(xb3);
    __syncthreads();

    float2* src = bufA;
    float2* dst = bufB;
    for (int it = 0; it < STEPS - 1; ++it) {
        {
            float2 acc = xb0;
            for (int e = rp0; e < rp1; ++e) {
                unsigned u = E[e];
                float w = __uint_as_float(u & 0xFFFFF000u);
                float2 x = src[u & (unsigned)NMASK];
                acc.x += w * x.x; acc.y += w * x.y;
            }
            dst[r0] = mml2(acc);
        }
        {
            float2 acc = xb1;
            for (int e = rp1; e < rp2; ++e) {
                unsigned u = E[e];
                float w = __uint_as_float(u & 0xFFFFF000u);
                float2 x = src[u & (unsigned)NMASK];
                acc.x += w * x.x; acc.y += w * x.y;
            }
            dst[r0 + 1] = mml2(acc);
        }
        {
            float2 acc = xb2;
            for (int e = rp2; e < rp3; ++e) {
                unsigned u = E[e];
                float w = __uint_as_float(u & 0xFFFFF000u);
                float2 x = src[u & (unsigned)NMASK];
                acc.x += w * x.x; acc.y += w * x.y;
            }
            dst[r0 + 2] = mml2(acc);
        }
        {
            float2 acc = xb3;
            for (int e = rp3; e < rp4; ++e) {
                unsigned u = E[e];
                float w = __uint_as_float(u & 0xFFFFF000u);
                float2 x = src[u & (unsigned)NMASK];
                acc.x += w * x.x; acc.y += w * x.y;
            }
            dst[r0 + 3] = mml2(acc);
        }
        __syncthreads();
        float2* t = src; src = dst; dst = t;
    }

    // final state is in src (after last swap); write both columns coalesced
    float2 f0 = src[r0], f1 = src[r0 + 1], f2 = src[r0 + 2], f3 = src[r0 + 3];
    float* o0 = out + (size_t)colb * N_NODES;
    float* o1 = out + (size_t)(colb + 1) * N_NODES;
    ((float4*)o0)[tid] = make_float4(f0.x, f1.x, f2.x, f3.x);
    ((float4*)o1)[tid] = make_float4(f0.y, f1.y, f2.y, f3.y);
}

extern "C" void kernel_launch(void* const* d_in, const int* in_sizes, int n_in,
                              void* d_out, int out_size, void* d_ws, size_t ws_size,
                              hipStream_t stream) {
    const float* X_full = nullptr;
    const float* W      = nullptr;
    const float* bias   = nullptr;
    for (int i = 0; i < n_in; ++i) {
        if      (in_sizes[i] == N_NODES * N_NODES) W      = (const float*)d_in[i];
        else if (in_sizes[i] == BATCH * N_NODES)   X_full = (const float*)d_in[i];
        else if (in_sizes[i] == N_NODES)           bias   = (const float*)d_in[i];
    }

    char* ws = (char*)d_ws;
    int*      deg    = (int*)(ws);
    int*      cursor = (int*)(ws + 16384);
    int*      rowptr = (int*)(ws + 32768);
    unsigned* E      = (unsigned*)(ws + 49408);

    zero_meta   <<<(2 * N_NODES + 255) / 256, 256, 0, stream>>>(deg);
    count_deg   <<<(N_NODES * N_NODES) / 256, 256, 0, stream>>>(W, deg);
    scan_rowptr <<<1, 1024, 0, stream>>>(deg, rowptr);
    scatter_edges<<<(N_NODES * N_NODES) / 256, 256, 0, stream>>>(W, rowptr, cursor, E);
    iterate_kernel<<<BATCH / 2, 1024, 0, stream>>>(X_full, bias, E, rowptr,
                                                   (float*)d_out);
}

// Round 4
// 1504.294 us; speedup vs baseline: 28.0696x; 10.0451x over previous
//
#include <hip/hip_runtime.h>
#include <stdint.h>

#define N_NODES 4096
#define BATCH   512
#define STEPS   120
#define LEAK    0.01f
#define NMASK   4095u

// ws layout:
//   deg    : int[4096]   @ 0
//   cursor : int[4096]   @ 16384
//   meta   : int[16]     @ 32768    meta[0] = k4max (number of 4-slot groups)
//   E      : u32 ELL     @ 36864    [group][node][4], group = k/4
#define OFF_CURSOR 16384
#define OFF_META   32768
#define OFF_E      36864
#define MAX_GROUPS 19                      // iterate prefetches group k4max <= 19
#define ZERO_GROUPS (MAX_GROUPS + 1)       // zero one extra group for prefetch
#define WS_WORDS (OFF_E / 4 + ZERO_GROUPS * N_NODES * 4)   // 336,896 u32

__global__ void zero_ws(unsigned* __restrict__ p, int n) {
    int i = (int)(blockIdx.x * 1024 + threadIdx.x);
    if (i < n) p[i] = 0u;
}

__global__ void count_deg(const float* __restrict__ W, int* __restrict__ deg) {
    int idx = (int)(blockIdx.x * 256 + threadIdx.x);
    if (W[idx] != 0.0f) atomicAdd(&deg[idx >> 12], 1);
}

__global__ void max_deg(const int* __restrict__ deg, int* __restrict__ meta) {
    __shared__ int sm[1024];
    int tid = (int)threadIdx.x;
    int b = tid * 4;
    int m = max(max(deg[b], deg[b + 1]), max(deg[b + 2], deg[b + 3]));
    sm[tid] = m;
    __syncthreads();
    for (int o = 512; o > 0; o >>= 1) {
        if (tid < o) sm[tid] = max(sm[tid], sm[tid + o]);
        __syncthreads();
    }
    if (tid == 0) {
        int g = (sm[0] + 3) >> 2;
        meta[0] = g > MAX_GROUPS ? MAX_GROUPS : g;
    }
}

__global__ void scatter_edges(const float* __restrict__ W,
                              int* __restrict__ cursor,
                              unsigned* __restrict__ E) {
    int idx = (int)(blockIdx.x * 256 + threadIdx.x);
    float w = W[idx];
    if (w != 0.0f) {
        int t = idx >> 12;
        unsigned s = (unsigned)idx & NMASK;
        int k = atomicAdd(&cursor[t], 1);
        if (k < MAX_GROUPS * 4) {
            unsigned wb = (__float_as_uint(w) + 0x800u) & 0xFFFFF000u; // RN 12-bit
            E[(((unsigned)(k >> 2) * N_NODES + (unsigned)t) << 2) | (unsigned)(k & 3)]
                = wb | s;
        }
    }
}

__device__ __forceinline__ float mml_f(float x) {
    float y = (x < 0.0f) ? (LEAK * x) : x;
    if (x > 0.5f) y = 1.0f - 0.25f / x;    // x>0.5 => max(x,0.5)=x
    return y;
}
__device__ __forceinline__ float2 mml2(float2 v) {
    return make_float2(mml_f(v.x), mml_f(v.y));
}

#define EDGE1(u, acc) {                                        \
    float w = __uint_as_float((u) & 0xFFFFF000u);              \
    float2 x = src[(u) & NMASK];                               \
    acc.x += w * x.x; acc.y += w * x.y; }
#define EDGE4(c, acc) { EDGE1(c.x, acc) EDGE1(c.y, acc) EDGE1(c.z, acc) EDGE1(c.w, acc) }

// One block = 2 batch columns; thread owns nodes {tid, tid+1024, tid+2048,
// tid+3072}; coalesced ELL edge stream with 1-group software prefetch;
// double-buffered X in LDS; zero atomics; one barrier per step.
__global__ void __launch_bounds__(1024, 4)
iterate_kernel(const float* __restrict__ X_full,   // (512, 4096) row-major
               const float* __restrict__ bias,     // (4096)
               const unsigned* __restrict__ E,
               const int* __restrict__ meta,
               float* __restrict__ out) {          // (512, 4096) row-major
    __shared__ float2 bufA[N_NODES];               // 32 KB
    __shared__ float2 bufB[N_NODES];               // 32 KB

    const int tid  = (int)threadIdx.x;             // 0..1023
    const int colb = (int)blockIdx.x * 2;
    const int k4max = meta[0];                     // uniform, <= 19
    const uint4* Eb = (const uint4*)E;             // [group][node]

    const int n0 = tid, n1 = tid + 1024, n2 = tid + 2048, n3 = tid + 3072;

    const float* x0r = X_full + (size_t)colb * N_NODES;
    const float* x1r = x0r + N_NODES;
    float b0 = bias[n0], b1 = bias[n1], b2 = bias[n2], b3 = bias[n3];
    float2 xb0 = make_float2(x0r[n0] + b0, x1r[n0] + b0);
    float2 xb1 = make_float2(x0r[n1] + b1, x1r[n1] + b1);
    float2 xb2 = make_float2(x0r[n2] + b2, x1r[n2] + b2);
    float2 xb3 = make_float2(x0r[n3] + b3, x1r[n3] + b3);

    // X1 = mml(X_bias)
    bufA[n0] = mml2(xb0); bufA[n1] = mml2(xb1);
    bufA[n2] = mml2(xb2); bufA[n3] = mml2(xb3);
    __syncthreads();

    float2* src = bufA;
    float2* dst = bufB;
    for (int it = 0; it < STEPS - 1; ++it) {
        float2 a0 = xb0, a1 = xb1, a2 = xb2, a3 = xb3;
        uint4 c0 = Eb[n0], c1 = Eb[n1], c2 = Eb[n2], c3 = Eb[n3];
        for (int g = 0; g < k4max; ++g) {
            const uint4* nb = Eb + (size_t)(g + 1) * N_NODES;  // prefetch next
            uint4 p0 = nb[n0], p1 = nb[n1], p2 = nb[n2], p3 = nb[n3];
            EDGE4(c0, a0)
            EDGE4(c1, a1)
            EDGE4(c2, a2)
            EDGE4(c3, a3)
            c0 = p0; c1 = p1; c2 = p2; c3 = p3;
        }
        dst[n0] = mml2(a0); dst[n1] = mml2(a1);
        dst[n2] = mml2(a2); dst[n3] = mml2(a3);
        __syncthreads();
        float2* t = src; src = dst; dst = t;
    }

    float2 f0 = src[n0], f1 = src[n1], f2 = src[n2], f3 = src[n3];
    float* o0 = out + (size_t)colb * N_NODES;
    float* o1 = o0 + N_NODES;
    o0[n0] = f0.x; o0[n1] = f1.x; o0[n2] = f2.x; o0[n3] = f3.x;
    o1[n0] = f0.y; o1[n1] = f1.y; o1[n2] = f2.y; o1[n3] = f3.y;
}

extern "C" void kernel_launch(void* const* d_in, const int* in_sizes, int n_in,
                              void* d_out, int out_size, void* d_ws, size_t ws_size,
                              hipStream_t stream) {
    const float* X_full = nullptr;
    const float* W      = nullptr;
    const float* bias   = nullptr;
    for (int i = 0; i < n_in; ++i) {
        if      (in_sizes[i] == N_NODES * N_NODES) W      = (const float*)d_in[i];
        else if (in_sizes[i] == BATCH * N_NODES)   X_full = (const float*)d_in[i];
        else if (in_sizes[i] == N_NODES)           bias   = (const float*)d_in[i];
    }

    char* ws = (char*)d_ws;
    int*      deg    = (int*)(ws);
    int*      cursor = (int*)(ws + OFF_CURSOR);
    int*      meta   = (int*)(ws + OFF_META);
    unsigned* E      = (unsigned*)(ws + OFF_E);

    zero_ws      <<<(WS_WORDS + 1023) / 1024, 1024, 0, stream>>>((unsigned*)ws, WS_WORDS);
    count_deg    <<<(N_NODES * N_NODES) / 256, 256, 0, stream>>>(W, deg);
    max_deg      <<<1, 1024, 0, stream>>>(deg, meta);
    scatter_edges<<<(N_NODES * N_NODES) / 256, 256, 0, stream>>>(W, cursor, E);
    iterate_kernel<<<BATCH / 2, 1024, 0, stream>>>(X_full, bias, E, meta,
                                                   (float*)d_out);
}

// Round 5
// 1216.674 us; speedup vs baseline: 34.7053x; 1.2364x over previous
//
#include <hip/hip_runtime.h>
#include <stdint.h>

#define N_NODES 4096
#define BATCH   512
#define STEPS   120
#define LEAK    0.01f
#define NMASK   4095u
#define MAXG    19                 // max 4-slot groups per row (deg <= 76)
#define ALLOCG  20                 // +1 group so prefetch of g+1 stays in-bounds

// ws layout (bytes):
#define OFF_DEG    0               // int[4096]
#define OFF_CURSOR 16384           // int[4096]
#define OFF_HIST   32768           // int[256]
#define OFF_CNT    33792           // int[256]
#define OFF_GMAX   34816           // int[64]   max degree per (band,slice)
#define OFF_BOUNDS 35072           // int[64]   group count per (band,slice)
#define OFF_START  35328           // int[256]  exclusive scan of hist
#define OFF_POS    36352           // int[4096] node -> permuted position
#define OFF_ORIG   52736           // int[4096] position -> node
#define OFF_E      69632           // u32 ELL [group][pos][4]
#define WS_BYTES   (OFF_E + ALLOCG * N_NODES * 16)   // 1,380,352
#define WS_WORDS   (WS_BYTES / 4)

__global__ void zero_ws(unsigned* __restrict__ p, int n) {
    int i = (int)(blockIdx.x * 1024 + threadIdx.x);
    if (i < n) p[i] = 0u;
}

__global__ void count_deg(const float* __restrict__ W, int* __restrict__ deg) {
    int idx = (int)(blockIdx.x * 256 + threadIdx.x);
    if (W[idx] != 0.0f) atomicAdd(&deg[idx >> 12], 1);
}

__global__ void hist_deg(const int* __restrict__ deg, int* __restrict__ hist) {
    int t = (int)(blockIdx.x * 256 + threadIdx.x);
    int d = deg[t]; if (d > 255) d = 255;
    atomicAdd(&hist[d], 1);
}

__global__ void scan_start(const int* __restrict__ hist, int* __restrict__ start) {
    __shared__ int sm[256];
    int tid = (int)threadIdx.x;
    int v = hist[tid];
    sm[tid] = v;
    __syncthreads();
    for (int o = 1; o < 256; o <<= 1) {
        int u = (tid >= o) ? sm[tid - o] : 0;
        __syncthreads();
        sm[tid] += u;
        __syncthreads();
    }
    start[tid] = sm[tid] - v;               // exclusive scan (ascending degree)
}

// Assign each node a rank by degree (counting sort), map rank -> position so
// that thread tid owns positions {tid, 1024+tid, 2048+tid, 3072+tid} =
// ranks {q, 2047-q, 2048+q, 4095-q} (balanced degree sum per thread).
__global__ void rank_assign(const int* __restrict__ deg,
                            const int* __restrict__ start,
                            int* __restrict__ cnt,
                            int* __restrict__ pos_of,
                            int* __restrict__ orig_of,
                            int* __restrict__ gmax) {
    int t = (int)(blockIdx.x * 256 + threadIdx.x);   // 4096 nodes
    int d = deg[t]; int dc = d > 255 ? 255 : d;
    int r = start[dc] + atomicAdd(&cnt[dc], 1);
    int p;
    if      (r < 1024) p = r;                        // band 0 (lightest)
    else if (r < 2048) p = 1024 + (2047 - r);        // band 1 (descending)
    else if (r < 3072) p = 2048 + (r - 2048);        // band 2
    else               p = 3072 + (4095 - r);        // band 3 (heaviest)
    pos_of[t] = p;
    orig_of[p] = t;
    atomicMax(&gmax[p >> 6], d);                     // per (band,slice) max deg
}

__global__ void finalize_bounds(const int* __restrict__ gmax,
                                int* __restrict__ bounds) {
    int i = (int)threadIdx.x;                        // 64
    int g = (gmax[i] + 3) >> 2;
    bounds[i] = g > MAXG ? MAXG : g;
}

__global__ void scatter_edges(const float* __restrict__ W,
                              const int* __restrict__ pos_of,
                              int* __restrict__ cursor,
                              unsigned* __restrict__ E) {
    int idx = (int)(blockIdx.x * 256 + threadIdx.x);
    float w = W[idx];
    if (w != 0.0f) {
        int t = idx >> 12;
        unsigned sI = (unsigned)idx & NMASK;
        int k = atomicAdd(&cursor[t], 1);
        if (k < MAXG * 4) {
            unsigned p = (unsigned)pos_of[t];
            unsigned wb = (__float_as_uint(w) + 0x800u) & 0xFFFFF000u; // RN 12-bit
            E[(((unsigned)(k >> 2) * N_NODES + p) << 2) | (unsigned)(k & 3)]
                = wb | (unsigned)pos_of[sI];
        }
    }
}

__device__ __forceinline__ float mml_f(float x) {
    float y = (x < 0.0f) ? (LEAK * x) : x;
    if (x > 0.5f) y = 1.0f - 0.25f / x;              // x>0.5 => max(x,0.5)=x
    return y;
}
__device__ __forceinline__ float2 mml2(float2 v) {
    return make_float2(mml_f(v.x), mml_f(v.y));
}

#define EDGE1(u, acc) {                                        \
    float w = __uint_as_float((u) & 0xFFFFF000u);              \
    float2 x = src[(u) & NMASK];                               \
    acc.x += w * x.x; acc.y += w * x.y; }
#define EDGE4(c, acc) { EDGE1(c.x, acc) EDGE1(c.y, acc) EDGE1(c.z, acc) EDGE1(c.w, acc) }

#define BAND(B, G, XB, T) {                                             \
    const uint4* base = Eb + (B * 1024 + tid);                          \
    float2 a = XB;                                                      \
    uint4 c = base[0];                                                  \
    for (int g = 0; g < G; ++g) {                                       \
        uint4 n = base[(size_t)(g + 1) * N_NODES];                      \
        EDGE4(c, a)                                                     \
        c = n;                                                          \
    }                                                                   \
    dst[B * 1024 + tid] = mml2(a); }

// One block = 2 batch columns; degree-balanced 4-band SELL; per-(band,slice)
// wave-uniform trip counts; coalesced E stream with 1-group prefetch;
// double-buffered X in LDS; zero atomics; one barrier per step.
__global__ void __launch_bounds__(1024, 4)
iterate_kernel(const float* __restrict__ X_full,     // (512, 4096) row-major
               const float* __restrict__ bias,       // (4096)
               const unsigned* __restrict__ E,
               const int* __restrict__ bounds,       // [4][16]
               const int* __restrict__ orig_of,      // pos -> node
               float* __restrict__ out) {            // (512, 4096) row-major
    __shared__ float2 bufA[N_NODES];                 // 32 KB
    __shared__ float2 bufB[N_NODES];                 // 32 KB

    const int tid  = (int)threadIdx.x;               // 0..1023
    const int colb = (int)blockIdx.x * 2;
    const int s    = tid >> 6;                       // wave slice 0..15
    const uint4* Eb = (const uint4*)E;

    const int G0 = bounds[s],      G1 = bounds[16 + s];
    const int G2 = bounds[32 + s], G3 = bounds[48 + s];

    const int t0 = orig_of[tid],        t1 = orig_of[1024 + tid];
    const int t2 = orig_of[2048 + tid], t3 = orig_of[3072 + tid];

    const float* x0r = X_full + (size_t)colb * N_NODES;
    const float* x1r = x0r + N_NODES;
    float b0 = bias[t0], b1 = bias[t1], b2 = bias[t2], b3 = bias[t3];
    float2 xb0 = make_float2(x0r[t0] + b0, x1r[t0] + b0);
    float2 xb1 = make_float2(x0r[t1] + b1, x1r[t1] + b1);
    float2 xb2 = make_float2(x0r[t2] + b2, x1r[t2] + b2);
    float2 xb3 = make_float2(x0r[t3] + b3, x1r[t3] + b3);

    // X1 = mml(X_bias), stored by permuted position
    bufA[tid]        = mml2(xb0);
    bufA[1024 + tid] = mml2(xb1);
    bufA[2048 + tid] = mml2(xb2);
    bufA[3072 + tid] = mml2(xb3);
    __syncthreads();

    float2* src = bufA;
    float2* dst = bufB;
    for (int it = 0; it < STEPS - 1; ++it) {
        BAND(0, G0, xb0, t0)
        BAND(1, G1, xb1, t1)
        BAND(2, G2, xb2, t2)
        BAND(3, G3, xb3, t3)
        __syncthreads();
        float2* t = src; src = dst; dst = t;
    }

    float2 f0 = src[tid],        f1 = src[1024 + tid];
    float2 f2 = src[2048 + tid], f3 = src[3072 + tid];
    float* o0 = out + (size_t)colb * N_NODES;
    float* o1 = o0 + N_NODES;
    o0[t0] = f0.x; o0[t1] = f1.x; o0[t2] = f2.x; o0[t3] = f3.x;
    o1[t0] = f0.y; o1[t1] = f1.y; o1[t2] = f2.y; o1[t3] = f3.y;
}

extern "C" void kernel_launch(void* const* d_in, const int* in_sizes, int n_in,
                              void* d_out, int out_size, void* d_ws, size_t ws_size,
                              hipStream_t stream) {
    const float* X_full = nullptr;
    const float* W      = nullptr;
    const float* bias   = nullptr;
    for (int i = 0; i < n_in; ++i) {
        if      (in_sizes[i] == N_NODES * N_NODES) W      = (const float*)d_in[i];
        else if (in_sizes[i] == BATCH * N_NODES)   X_full = (const float*)d_in[i];
        else if (in_sizes[i] == N_NODES)           bias   = (const float*)d_in[i];
    }

    char* ws = (char*)d_ws;
    int*      deg    = (int*)(ws + OFF_DEG);
    int*      cursor = (int*)(ws + OFF_CURSOR);
    int*      hist   = (int*)(ws + OFF_HIST);
    int*      cnt    = (int*)(ws + OFF_CNT);
    int*      gmax   = (int*)(ws + OFF_GMAX);
    int*      bounds = (int*)(ws + OFF_BOUNDS);
    int*      start  = (int*)(ws + OFF_START);
    int*      pos_of = (int*)(ws + OFF_POS);
    int*      orig   = (int*)(ws + OFF_ORIG);
    unsigned* E      = (unsigned*)(ws + OFF_E);

    zero_ws        <<<(WS_WORDS + 1023) / 1024, 1024, 0, stream>>>((unsigned*)ws, WS_WORDS);
    count_deg      <<<(N_NODES * N_NODES) / 256, 256, 0, stream>>>(W, deg);
    hist_deg       <<<N_NODES / 256, 256, 0, stream>>>(deg, hist);
    scan_start     <<<1, 256, 0, stream>>>(hist, start);
    rank_assign    <<<N_NODES / 256, 256, 0, stream>>>(deg, start, cnt, pos_of, orig, gmax);
    finalize_bounds<<<1, 64, 0, stream>>>(gmax, bounds);
    scatter_edges  <<<(N_NODES * N_NODES) / 256, 256, 0, stream>>>(W, pos_of, cursor, E);
    iterate_kernel <<<BATCH / 2, 1024, 0, stream>>>(X_full, bias, E, bounds, orig,
                                                    (float*)d_out);
}